// Round 9
// baseline (1421.955 us; speedup 1.0000x reference)
//
#include <hip/hip_runtime.h>

namespace {

using v4f    = __attribute__((ext_vector_type(4))) float;
using short8 = __attribute__((ext_vector_type(8))) short;

constexpr int T = 256;

__device__ __forceinline__ float frcp(float x) { return __builtin_amdgcn_rcpf(x); }
__device__ __forceinline__ float sgm(float x) { return frcp(1.f + __expf(-x)); }
__device__ __forceinline__ float ftanh(float x) {
  const float e = __expf(-2.f * x);
  return (1.f - e) * frcp(1.f + e);
}
__device__ __forceinline__ unsigned short f2bf(float f) {
  unsigned x = __float_as_uint(f);
  return (unsigned short)((x + 0x7FFFu + ((x >> 16) & 1u)) >> 16);
}
__device__ __forceinline__ float bf2f(unsigned short s) {
  return __uint_as_float((unsigned)s << 16);
}
__device__ __forceinline__ void cvt8(const float* w, short8& hi, short8& lo) {
#pragma unroll
  for (int j = 0; j < 8; ++j) {
    const unsigned short h = f2bf(w[j]);
    hi[j] = (short)h;
    lo[j] = (short)f2bf(w[j] - bf2f(h));
  }
}

#define MFMA(A, B, C) __builtin_amdgcn_mfma_f32_16x16x32_bf16((A), (B), (C), 0, 0, 0)

__global__ __launch_bounds__(512, 1) void seq2seq_kernel(
    const float* __restrict__ enc_x, const float* __restrict__ dec_x,
    const float* __restrict__ eWih0, const float* __restrict__ eWhh0, const float* __restrict__ eb0,
    const float* __restrict__ eWih1, const float* __restrict__ eWhh1, const float* __restrict__ eb1,
    const float* __restrict__ eWih2, const float* __restrict__ eWhh2, const float* __restrict__ eb2,
    const float* __restrict__ dWih0, const float* __restrict__ dWhh0, const float* __restrict__ db0,
    const float* __restrict__ dWih1, const float* __restrict__ dWhh1, const float* __restrict__ db1,
    const float* __restrict__ dWih2, const float* __restrict__ dWhh2, const float* __restrict__ db2,
    const float* __restrict__ fcW, const float* __restrict__ fcb,
    float* __restrict__ out) {
  // h state, double-buffered on t-parity: [parity][hi/lo][arr: h0,h1,h2,yp][col][k pad 72]
  __shared__ __align__(16) unsigned short hb[2][2][4][16][72];  // 36 KB
  __shared__ float xs[2][4][T];        // 8 KB
  __shared__ float biasq[6][64][4];    // 6 KB   bias pre-swizzled [row][unit][gate]
  __shared__ float fcring[32][8][5];   // 5 KB   fc partials ring (pad 5 vs bank)

  const int tid = threadIdx.x;
  const int w = tid >> 6, l = tid & 63;
  const int col = l & 15, q = l >> 4;
  const int b0 = blockIdx.x * 4;

  // ---- stage x as [sel][g][t]; biases swizzled; zero h state ----
  for (int i = tid; i < 4 * T; i += 512) {
    ((float*)xs[0])[i] = enc_x[b0 * T + i];
    ((float*)xs[1])[i] = dec_x[b0 * T + i];
  }
  if (tid < 256) {
    const int u_ = tid & 63, r_ = tid >> 6;
    biasq[0][u_][r_] = eb0[r_ * 64 + u_];
    biasq[1][u_][r_] = eb1[r_ * 64 + u_];
    biasq[2][u_][r_] = eb2[r_ * 64 + u_];
    biasq[3][u_][r_] = db0[r_ * 64 + u_];
    biasq[4][u_][r_] = db1[r_ * 64 + u_];
    biasq[5][u_][r_] = db2[r_ * 64 + u_];
  }
  for (int i = tid; i < (int)(sizeof(hb) / 4); i += 512) ((unsigned*)hb)[i] = 0u;

  float cst[3][2] = {{0.f, 0.f}, {0.f, 0.f}, {0.f, 0.f}};  // cell state in-lane
  float fcw_[2] = {0.f, 0.f};
  const float fcb0 = fcb[0];

  // ---- resident A-frags, gate-interleaved rows: vr = (m&3)*64 + tile*4 + (m>>2) ----
  short8 Ah[6][2][2], Al[6][2][2];
  v4f xwc[2];

#define BUILD(S, W)                                                          \
  _Pragma("unroll") for (int mt = 0; mt < 2; ++mt)                           \
  _Pragma("unroll") for (int kc = 0; kc < 2; ++kc) {                         \
    const int vr = (col & 3) * 64 + (2 * w + mt) * 4 + (col >> 2);           \
    cvt8((W) + vr * 64 + kc * 32 + q * 8, Ah[S][mt][kc], Al[S][mt][kc]);     \
  }
#define BUILDU(S, W)                                                         \
  _Pragma("unroll") for (int mt = 0; mt < 2; ++mt)                           \
  _Pragma("unroll") for (int kc = 0; kc < 2; ++kc) {                         \
    const int vr = (col & 3) * 64 + (2 * w + mt) * 4 + (col >> 2);           \
    float tw[8];                                                             \
    const float* p = (W) + vr * 65 + 1 + kc * 32 + q * 8;                    \
    _Pragma("unroll") for (int j = 0; j < 8; ++j) tw[j] = p[j];              \
    cvt8(tw, Ah[S][mt][kc], Al[S][mt][kc]);                                  \
  }

  BUILD(0, eWhh0) BUILD(1, eWih1) BUILD(2, eWhh1) BUILD(3, eWih2) BUILD(4, eWhh2)
#pragma unroll
  for (int mt = 0; mt < 2; ++mt) {
    const int U = (2 * w + mt) * 4 + q;
    xwc[mt] = (v4f){eWih0[U], eWih0[64 + U], eWih0[128 + U], eWih0[192 + U]};
  }

  __syncthreads();

#define ACLR                                                                 \
  v4f acc[2][2];                                                             \
  acc[0][0] = (v4f){0.f, 0.f, 0.f, 0.f}; acc[0][1] = (v4f){0.f, 0.f, 0.f, 0.f}; \
  acc[1][0] = (v4f){0.f, 0.f, 0.f, 0.f}; acc[1][1] = (v4f){0.f, 0.f, 0.f, 0.f};

#define LDB4N(N, AR, RP)                                                     \
  const short8 bh0##N = *(const short8*)&hb[(RP)][0][AR][col][q * 8];        \
  const short8 bl0##N = *(const short8*)&hb[(RP)][1][AR][col][q * 8];        \
  const short8 bh1##N = *(const short8*)&hb[(RP)][0][AR][col][32 + q * 8];   \
  const short8 bl1##N = *(const short8*)&hb[(RP)][1][AR][col][32 + q * 8];

#define TRIO(S, MT, KC, BH, BL)                                              \
  acc[MT][KC] = MFMA(Ah[S][MT][KC], (BH), acc[MT][KC]);                      \
  acc[MT][KC] = MFMA(Ah[S][MT][KC], (BL), acc[MT][KC]);                      \
  acc[MT][KC] = MFMA(Al[S][MT][KC], (BH), acc[MT][KC]);

#define MATN(S, N)                                                           \
  TRIO(S, 0, 0, bh0##N, bl0##N) TRIO(S, 1, 0, bh0##N, bl0##N)                \
  TRIO(S, 0, 1, bh1##N, bl1##N) TRIO(S, 1, 1, bh1##N, bl1##N)

// In-lane gate update: acc[mt][r] = gates (i,f,g,o) of unit U=(2w+mt)*4+q.
#define GUPD(L, BROW, XF, XSEL, YPDUP, DOFC, TP)                             \
  {                                                                          \
    float xv = 0.f;                                                          \
    if (XF) xv = xs[XSEL][col & 3][t];                                       \
    float prl = 0.f; (void)prl;                                              \
    _Pragma("unroll") for (int mt = 0; mt < 2; ++mt) {                       \
      const int U = (2 * w + mt) * 4 + q;                                    \
      v4f z = acc[mt][0] + acc[mt][1] + *(const v4f*)&biasq[BROW][U][0];     \
      if (XF) z += xwc[mt] * xv;                                             \
      const float ii = sgm(z[0]), ff = sgm(z[1]);                            \
      const float gg = ftanh(z[2]), oo = sgm(z[3]);                          \
      const float cn = ff * cst[L][mt] + ii * gg;                            \
      cst[L][mt] = cn;                                                       \
      const float hn = oo * ftanh(cn);                                       \
      const unsigned short hh = f2bf(hn);                                    \
      const unsigned short hl2 = f2bf(hn - bf2f(hh));                        \
      if (col < 4) {                                                         \
        hb[TP][0][L][col][U] = hh;                                           \
        hb[TP][1][L][col][U] = hl2;                                          \
        if (YPDUP) { hb[TP][0][3][col][U] = hh; hb[TP][1][3][col][U] = hl2; }\
      }                                                                      \
      if (DOFC) prl += fcw_[mt] * hn;                                        \
    }                                                                        \
    if (DOFC) {                                                              \
      prl += __shfl_xor(prl, 16, 64);                                        \
      prl += __shfl_xor(prl, 32, 64);                                        \
      if (q == 0 && col < 4) fcring[t & 31][w][col] = prl;                   \
    }                                                                        \
  }                                                                          \
  __syncthreads();

#define ENCSTEP(TP)                                                          \
  { ACLR LDB4N(a, 0, (TP) ^ 1) MATN(0, a) GUPD(0, 0, 1, 0, 0, 0, TP) }       \
  { ACLR LDB4N(a, 0, TP) LDB4N(b, 1, (TP) ^ 1) MATN(1, a) MATN(2, b)         \
    GUPD(1, 1, 0, 0, 0, 0, TP) }                                             \
  { ACLR LDB4N(a, 1, TP) LDB4N(b, 2, (TP) ^ 1) MATN(3, a) MATN(4, b)         \
    GUPD(2, 2, 0, 0, 0, 0, TP) }

#define DECSTEP(TP)                                                          \
  { ACLR LDB4N(a, 3, (TP) ^ 1) LDB4N(b, 0, (TP) ^ 1) MATN(5, a) MATN(0, b)   \
    GUPD(0, 3, 1, 1, 0, 0, TP) }                                             \
  { ACLR LDB4N(a, 0, TP) LDB4N(b, 1, (TP) ^ 1) MATN(1, a) MATN(2, b)         \
    GUPD(1, 4, 0, 0, 0, 0, TP) }                                             \
  { ACLR LDB4N(a, 1, TP) LDB4N(b, 2, (TP) ^ 1) MATN(3, a) MATN(4, b)         \
    GUPD(2, 5, 0, 0, 1, 1, TP) }

  // ---------------- Encoder ----------------
#pragma clang loop unroll(disable)
  for (int t2 = 0; t2 < T; t2 += 2) {
    { const int t = t2;     ENCSTEP(0) }
    { const int t = t2 + 1; ENCSTEP(1) }
  }

  // ---- decoder weights (rebuild; slot 5 = y-columns of dWih0) ----
  BUILD(0, dWhh0) BUILD(1, dWih1) BUILD(2, dWhh1) BUILD(3, dWih2) BUILD(4, dWhh2)
  BUILDU(5, dWih0)
#pragma unroll
  for (int mt = 0; mt < 2; ++mt) {
    const int U = (2 * w + mt) * 4 + q;
    xwc[mt] = (v4f){dWih0[U * 65], dWih0[(64 + U) * 65],
                    dWih0[(128 + U) * 65], dWih0[(192 + U) * 65]};
    fcw_[mt] = fcW[U];
  }

  // ---------------- Decoder ----------------
#pragma clang loop unroll(disable)
  for (int t2 = 0; t2 < T; t2 += 2) {
    {
      const int t = t2;
      if (t > 0 && (t & 31) == 0 && tid < 128) {  // flush preds of t-32..t-1
        const int ti = tid >> 2, c4 = tid & 3;
        float s = fcb0;
#pragma unroll
        for (int ww = 0; ww < 8; ++ww) s += fcring[ti][ww][c4];
        out[(b0 + c4) * T + (t - 32) + ti] = s;
      }
      DECSTEP(0)
    }
    { const int t = t2 + 1; DECSTEP(1) }
  }
  // final flush: t = 224..255 (ring fully written; last barrier passed)
  if (tid < 128) {
    const int ti = tid >> 2, c4 = tid & 3;
    float s = fcb0;
#pragma unroll
    for (int ww = 0; ww < 8; ++ww) s += fcring[ti][ww][c4];
    out[(b0 + c4) * T + 224 + ti] = s;
  }

#undef DECSTEP
#undef ENCSTEP
#undef GUPD
#undef MATN
#undef TRIO
#undef LDB4N
#undef ACLR
#undef BUILDU
#undef BUILD
}

}  // namespace

extern "C" void kernel_launch(void* const* d_in, const int* in_sizes, int n_in,
                              void* d_out, int out_size, void* d_ws, size_t ws_size,
                              hipStream_t stream) {
  const float* enc_x = (const float*)d_in[0];
  const float* dec_x = (const float*)d_in[1];
  const float* eWih0 = (const float*)d_in[2];
  const float* eWhh0 = (const float*)d_in[3];
  const float* eb0   = (const float*)d_in[4];
  const float* eWih1 = (const float*)d_in[5];
  const float* eWhh1 = (const float*)d_in[6];
  const float* eb1   = (const float*)d_in[7];
  const float* eWih2 = (const float*)d_in[8];
  const float* eWhh2 = (const float*)d_in[9];
  const float* eb2   = (const float*)d_in[10];
  const float* dWih0 = (const float*)d_in[11];
  const float* dWhh0 = (const float*)d_in[12];
  const float* db0   = (const float*)d_in[13];
  const float* dWih1 = (const float*)d_in[14];
  const float* dWhh1 = (const float*)d_in[15];
  const float* db1   = (const float*)d_in[16];
  const float* dWih2 = (const float*)d_in[17];
  const float* dWhh2 = (const float*)d_in[18];
  const float* db2   = (const float*)d_in[19];
  const float* fcW   = (const float*)d_in[20];
  const float* fcb   = (const float*)d_in[21];
  float* out = (float*)d_out;

  seq2seq_kernel<<<dim3(256), dim3(512), 0, stream>>>(
      enc_x, dec_x, eWih0, eWhh0, eb0, eWih1, eWhh1, eb1, eWih2, eWhh2, eb2,
      dWih0, dWhh0, db0, dWih1, dWhh1, db1, dWih2, dWhh2, db2, fcW, fcb, out);
}

// Round 10
// 1140.690 us; speedup vs baseline: 1.2466x; 1.2466x over previous
//
#include <hip/hip_runtime.h>

namespace {

using v4f    = __attribute__((ext_vector_type(4))) float;
using short8 = __attribute__((ext_vector_type(8))) short;

constexpr int T = 256, GB = 4;

__device__ __forceinline__ float frcp(float x) { return __builtin_amdgcn_rcpf(x); }
__device__ __forceinline__ float sgm(float x) { return frcp(1.f + __expf(-x)); }
__device__ __forceinline__ float ftanh(float x) {
  const float e = __expf(-2.f * x);
  return (1.f - e) * frcp(1.f + e);
}
__device__ __forceinline__ unsigned short f2bf(float f) {
  unsigned x = __float_as_uint(f);
  return (unsigned short)((x + 0x7FFFu + ((x >> 16) & 1u)) >> 16);
}
__device__ __forceinline__ float bf2f(unsigned short s) {
  return __uint_as_float((unsigned)s << 16);
}
__device__ __forceinline__ void cvt8(const float* w, short8& hi, short8& lo) {
#pragma unroll
  for (int j = 0; j < 8; ++j) {
    const unsigned short h = f2bf(w[j]);
    hi[j] = (short)h;
    lo[j] = (short)f2bf(w[j] - bf2f(h));
  }
}

#define MFMA(A, B, C) __builtin_amdgcn_mfma_f32_16x16x32_bf16((A), (B), (C), 0, 0, 0)

__global__ __launch_bounds__(512, 1) void seq2seq_kernel(
    const float* __restrict__ enc_x, const float* __restrict__ dec_x,
    const float* __restrict__ eWih0, const float* __restrict__ eWhh0, const float* __restrict__ eb0,
    const float* __restrict__ eWih1, const float* __restrict__ eWhh1, const float* __restrict__ eb1,
    const float* __restrict__ eWih2, const float* __restrict__ eWhh2, const float* __restrict__ eb2,
    const float* __restrict__ dWih0, const float* __restrict__ dWhh0, const float* __restrict__ db0,
    const float* __restrict__ dWih1, const float* __restrict__ dWhh1, const float* __restrict__ db1,
    const float* __restrict__ dWih2, const float* __restrict__ dWhh2, const float* __restrict__ db2,
    const float* __restrict__ fcW, const float* __restrict__ fcb,
    float* __restrict__ out) {
  // h (+yp) as bf16, hi/lo packed into B COLUMNS: col g = hi(batch g), col g+8 = lo.
  __shared__ __align__(16) unsigned short hb[4][16][72];  // 9.2 KB (arr: h0,h1,h2,yp)
  __shared__ float zl[GB][264];                           // 4.2 KB  K-complete z
  __shared__ float xs[2][GB][T];                          // 8 KB    staged enc_x/dec_x
  __shared__ float bias[6][256];                          // 6 KB

  const int tid = threadIdx.x;
  const int w = tid >> 6, l = tid & 63;
  const int mt0 = w * 2;          // wave owns M-tiles mt0, mt0+1 (gate rows 32w..32w+31)
  const int col = l & 15;         // B col: 0-3 batch hi, 8-11 batch lo
  const int q = l >> 4;           // k-subgroup / C-row group
  const int u = tid & 63, g = (tid >> 6) & 3;  // update mapping (tid<256)
  const int b0 = blockIdx.x * GB;

  // ---- stage x, biases; zero hb (cols 4-7, 12-15 stay zero forever) ----
  for (int i = tid; i < GB * T; i += 512) {
    ((float*)xs[0])[i] = enc_x[b0 * T + i];
    ((float*)xs[1])[i] = dec_x[b0 * T + i];
  }
  if (tid < 256) {
    bias[0][tid] = eb0[tid]; bias[1][tid] = eb1[tid]; bias[2][tid] = eb2[tid];
    bias[3][tid] = db0[tid]; bias[4][tid] = db1[tid]; bias[5][tid] = db2[tid];
  }
  for (int i = tid; i < (int)(sizeof(hb) / 4); i += 512) ((unsigned*)hb)[i] = 0u;

  float cr0 = 0.f, cr1 = 0.f, cr2 = 0.f;  // cell state (update threads)
  const float fcw = fcW[u];
  const float fcbv = fcb[0];

  // ---- resident A-frags: 6 mats x 2 Mtiles x 2 Kchunks x (hi,lo) = 192 regs ----
  short8 Ah[6][2][2], Al[6][2][2];
  float xwc[2][4];

#define BUILD(S, W)                                                           \
  _Pragma("unroll") for (int mt = 0; mt < 2; ++mt)                            \
  _Pragma("unroll") for (int kc = 0; kc < 2; ++kc)                            \
      cvt8((W) + ((mt0 + mt) * 16 + col) * 64 + kc * 32 + q * 8,              \
           Ah[S][mt][kc], Al[S][mt][kc]);

#define BUILDU(S, W, LD, OFF)                                                 \
  _Pragma("unroll") for (int mt = 0; mt < 2; ++mt)                            \
  _Pragma("unroll") for (int kc = 0; kc < 2; ++kc) {                          \
    float tw[8];                                                              \
    const float* p = (W) + ((mt0 + mt) * 16 + col) * (LD) + (OFF) + kc * 32 + q * 8; \
    _Pragma("unroll") for (int j = 0; j < 8; ++j) tw[j] = p[j];               \
    cvt8(tw, Ah[S][mt][kc], Al[S][mt][kc]);                                   \
  }

  // encoder slots: 0=Whh0 1=Wih1 2=Whh1 3=Wih2 4=Whh2
  BUILD(0, eWhh0) BUILD(1, eWih1) BUILD(2, eWhh1) BUILD(3, eWih2) BUILD(4, eWhh2)
#pragma unroll
  for (int mt = 0; mt < 2; ++mt)
#pragma unroll
    for (int r = 0; r < 4; ++r) xwc[mt][r] = eWih0[(mt0 + mt) * 16 + q * 4 + r];

  __syncthreads();

  // One B-frag per k-chunk; lane's column selects hi or lo automatically.
#define LDB2N(N, AR)                                                          \
  const short8 b0##N = *(const short8*)&hb[AR][col][q * 8];                   \
  const short8 b1##N = *(const short8*)&hb[AR][col][32 + q * 8];

#define DUO(S, MT, KC, B)                                                     \
  acc[MT] = MFMA(Ah[S][MT][KC], (B), acc[MT]);                                \
  acc[MT] = MFMA(Al[S][MT][KC], (B), acc[MT]);

#define MATN(S, N)                                                            \
  DUO(S, 0, 0, b0##N) DUO(S, 1, 0, b0##N)                                     \
  DUO(S, 0, 1, b1##N) DUO(S, 1, 1, b1##N)

  // Cross-lane combine: z[:,g] = C[:,g] (hi terms) + C[:,g+8] (lo terms).
#define CMB                                                                   \
  _Pragma("unroll") for (int mt = 0; mt < 2; ++mt)                            \
  _Pragma("unroll") for (int r = 0; r < 4; ++r)                               \
      acc[mt][r] += __shfl_xor(acc[mt][r], 8, 64);

#define ACLR                                                                  \
  v4f acc[2];                                                                 \
  acc[0] = (v4f){0.f, 0.f, 0.f, 0.f};                                         \
  acc[1] = (v4f){0.f, 0.f, 0.f, 0.f};

#define ZST                                                                   \
  if (col < 4) {                                                              \
    *(v4f*)&zl[col][(mt0 + 0) * 16 + q * 4] = acc[0];                         \
    *(v4f*)&zl[col][(mt0 + 1) * 16 + q * 4] = acc[1];                         \
  }

#define XFOLD(XSEL)                                                           \
  {                                                                           \
    const float xv = xs[XSEL][col & 3][t];                                    \
    _Pragma("unroll") for (int mt = 0; mt < 2; ++mt)                          \
    _Pragma("unroll") for (int r = 0; r < 4; ++r)                             \
        acc[mt][r] += xwc[mt][r] * xv;                                        \
  }

#define ZUPD(BROW, L, EXTRA)                                                  \
  __syncthreads();                                                            \
  if (tid < 256) {                                                            \
    const float z0 = bias[BROW][u]       + zl[g][u];                          \
    const float z1 = bias[BROW][u + 64]  + zl[g][u + 64];                     \
    const float z2 = bias[BROW][u + 128] + zl[g][u + 128];                    \
    const float z3 = bias[BROW][u + 192] + zl[g][u + 192];                    \
    const float ii = sgm(z0), ff = sgm(z1), gg = ftanh(z2), oo = sgm(z3);     \
    const float cn = ff * cr##L + ii * gg;                                    \
    cr##L = cn;                                                               \
    const float hn = oo * ftanh(cn);                                          \
    const unsigned short hh = f2bf(hn);                                       \
    const unsigned short hl2 = f2bf(hn - bf2f(hh));                           \
    hb[L][g][u] = hh;                                                         \
    hb[L][g + 8][u] = hl2;                                                    \
    EXTRA                                                                     \
  }                                                                           \
  __syncthreads();

#define PH1(S, AR, XSEL, BROW, L)                                             \
  {                                                                           \
    ACLR                                                                      \
    LDB2N(a, AR)                                                              \
    MATN(S, a)                                                                \
    CMB                                                                       \
    XFOLD(XSEL)                                                               \
    ZST                                                                       \
    ZUPD(BROW, L, )                                                           \
  }

#define PH2(SA, ARA, SB, ARB, XF, XSEL, BROW, L, EXTRA)                       \
  {                                                                           \
    ACLR                                                                      \
    LDB2N(a, ARA)                                                             \
    LDB2N(b, ARB)                                                             \
    MATN(SA, a)                                                               \
    MATN(SB, b)                                                               \
    CMB                                                                       \
    if (XF) XFOLD(XSEL)                                                       \
    ZST                                                                       \
    ZUPD(BROW, L, EXTRA)                                                      \
  }

  // ---------------- Encoder ----------------
#pragma clang loop unroll(disable)
  for (int t = 0; t < T; ++t) {
    PH1(0, 0, 0, 0, 0)                 // L0: Whh0·h0 + x·Wih0
    PH2(1, 0, 2, 1, 0, 0, 1, 1, )      // L1: Wih1·h0 + Whh1·h1
    PH2(3, 1, 4, 2, 0, 0, 2, 2, )      // L2: Wih2·h1 + Whh2·h2
  }

  // ---- decoder weights (rebuild; slot 5 = y-columns of dWih0) ----
  BUILD(0, dWhh0) BUILD(1, dWih1) BUILD(2, dWhh1) BUILD(3, dWih2) BUILD(4, dWhh2)
  BUILDU(5, dWih0, 65, 1)
#pragma unroll
  for (int mt = 0; mt < 2; ++mt)
#pragma unroll
    for (int r = 0; r < 4; ++r) xwc[mt][r] = dWih0[((mt0 + mt) * 16 + q * 4 + r) * 65];

  // ---------------- Decoder ----------------
#pragma clang loop unroll(disable)
  for (int t = 0; t < T; ++t) {
    PH2(5, 3, 0, 0, 1, 1, 3, 0, )      // L0: Wih0y·yp + Whh0·h0 + x·col0
    PH2(1, 0, 2, 1, 0, 0, 4, 1, )      // L1
    PH2(3, 1, 4, 2, 0, 0, 5, 2, {      // L2 + yp write + fc
      hb[3][g][u] = hh;
      hb[3][g + 8][u] = hl2;
      float pr = hn * fcw;
      _Pragma("unroll") for (int o = 32; o > 0; o >>= 1)
          pr += __shfl_down(pr, o, 64);
      if (u == 0) out[(b0 + g) * T + t] = pr + fcbv;
    })
  }
#undef PH2
#undef PH1
#undef ZUPD
#undef XFOLD
#undef ZST
#undef ACLR
#undef CMB
#undef MATN
#undef DUO
#undef LDB2N
#undef BUILDU
#undef BUILD
}

}  // namespace

extern "C" void kernel_launch(void* const* d_in, const int* in_sizes, int n_in,
                              void* d_out, int out_size, void* d_ws, size_t ws_size,
                              hipStream_t stream) {
  const float* enc_x = (const float*)d_in[0];
  const float* dec_x = (const float*)d_in[1];
  const float* eWih0 = (const float*)d_in[2];
  const float* eWhh0 = (const float*)d_in[3];
  const float* eb0   = (const float*)d_in[4];
  const float* eWih1 = (const float*)d_in[5];
  const float* eWhh1 = (const float*)d_in[6];
  const float* eb1   = (const float*)d_in[7];
  const float* eWih2 = (const float*)d_in[8];
  const float* eWhh2 = (const float*)d_in[9];
  const float* eb2   = (const float*)d_in[10];
  const float* dWih0 = (const float*)d_in[11];
  const float* dWhh0 = (const float*)d_in[12];
  const float* db0   = (const float*)d_in[13];
  const float* dWih1 = (const float*)d_in[14];
  const float* dWhh1 = (const float*)d_in[15];
  const float* db1   = (const float*)d_in[16];
  const float* dWih2 = (const float*)d_in[17];
  const float* dWhh2 = (const float*)d_in[18];
  const float* db2   = (const float*)d_in[19];
  const float* fcW   = (const float*)d_in[20];
  const float* fcb   = (const float*)d_in[21];
  float* out = (float*)d_out;

  seq2seq_kernel<<<dim3(256), dim3(512), 0, stream>>>(
      enc_x, dec_x, eWih0, eWhh0, eb0, eWih1, eWhh1, eb1, eWih2, eWhh2, eb2,
      dWih0, dWhh0, db0, dWih1, dWhh1, db1, dWih2, dWhh2, db2, fcW, fcb, out);
}